// Round 19
// baseline (371.494 us; speedup 1.0000x reference)
//
#include <hip/hip_runtime.h>

namespace {

constexpr int Bn = 8192;
constexpr int Tn = 365;
constexpr int Hn = 34;
constexpr int GB = 16;      // batches per block -> grid 512, 2 blocks/CU
constexpr int KP = 72;      // a_lds row stride in halves (144 B; 2-way banks)

constexpr float L2E = 1.44269504088896340736f;

typedef __attribute__((ext_vector_type(8))) _Float16 f16x8;  // 8 fp16 = 4 VGPR
typedef __attribute__((ext_vector_type(4))) float f32x4;     // 16x16 MFMA acc
typedef __attribute__((ext_vector_type(4), aligned(8))) _Float16 h16x4;  // b64 LDS read
typedef __attribute__((ext_vector_type(2), aligned(4))) _Float16 h16x2;
typedef __attribute__((ext_vector_type(4), aligned(4))) float f32x4u;    // 8B-aligned-safe store
typedef __attribute__((ext_vector_type(2), aligned(4))) float f32x2u;

__device__ __forceinline__ float fexp2(float v) { return __builtin_amdgcn_exp2f(v); }
__device__ __forceinline__ float frcp(float v)  { return __builtin_amdgcn_rcpf(v); }

// cross-wave LDS barrier WITHOUT a vmcnt drain: LDS writes drained (lgkmcnt),
// then raw s_barrier. Global stores/loads stay in flight across steps.
__device__ __forceinline__ void block_sync_lds() {
    __builtin_amdgcn_sched_barrier(0);
    asm volatile("s_waitcnt lgkmcnt(0)" ::: "memory");
    __builtin_amdgcn_s_barrier();
    __builtin_amdgcn_sched_barrier(0);
}

// FP16 K-layout (42 used of 64; pads stay zero). fp16 (e5m10): h,x,w in [-5,5]
// mid-range -> 4x finer than bf16; fp16 products exact in f32 MFMA accumulate.
// Weight rows PRE-SCALED by s(gate): -log2e (i,f,o) / +2*log2e (g):
//   sigmoid = rcp(1+exp2(acc)),  tanh = fma(-2, rcp(1+exp2(acc)), 1).
//   k 0-33 : h[j]   <-> fp16(s*w_hh[r][j])
//   k 34-36: x_h[i] <-> fp16(s*Wc[r][i])
//   k 37-39: x_l[i] <-> fp16(s*Wc[r][i])     (x_l = x - fp16(x))
//   k 40   : 1.0    <-> bias_h ;  k 41 : 1.0 <-> bias_l
//
// SWAPPED-OPERAND MFMA (R16): lane (kg,b) holds gates i,f,g,o of cell
// jl = 4*tau+kg, batch b -> cell update LANE-LOCAL. One s_barrier/step.
//
// R19: OUTPUT COALESCING. The per-lane scattered stores (64 distinct cache
// lines per wave-store; ~1100 cyc/CU/step of TA time — the R9-R18 invariant
// floor) are replaced by: gather h(t-1) from a_lds[cur] (already fp16 there),
// cvt, store float4 runs. 544 scattered dwords -> ~20 lines per block-step.

__global__ __launch_bounds__(256) void lstm_kernel(
    const float* __restrict__ x,      // [B,T,3]
    const float* __restrict__ fc0_w,  // [34,3]
    const float* __restrict__ fc0_b,  // [34]
    const float* __restrict__ w_ih,   // [136,34]
    const float* __restrict__ w_hh,   // [136,34]
    const float* __restrict__ b_ih,   // [136]
    const float* __restrict__ b_hh,   // [136]
    float* __restrict__ out)          // [B,T,34]
{
    __shared__ __align__(16) _Float16 a_lds[2][GB][KP]; // h/x operand, double-buffered

    const int tid  = threadIdx.x;
    const int lane = tid & 63;
    const int wv   = tid >> 6;      // wave id
    const int b    = lane & 15;     // batch (D col); tile-row rho when building W
    const int kg   = lane >> 4;     // k-group; D-row group

    // cell partition across waves: {9,9,8,8}
    const int nc   = (wv < 2) ? 9 : 8;
    const int base = (wv < 2) ? 9 * wv : 18 + 8 * (wv - 2);

    // ---- one-time: weight A-fragments (3 N-tiles x 2 K-chunks), prescaled fp16 ----
    f16x8 Wt[3][2];
    #pragma unroll
    for (int tau = 0; tau < 3; ++tau) {
        const int rhat = 16 * tau + b;
        const int jl = rhat >> 2, g = rhat & 3;
        const int r = (jl < nc) ? g * Hn + (base + jl) : -1;
        const float s = (g == 2) ? (2.f * L2E) : (-L2E);
        float swc[3] = {0.f, 0.f, 0.f};
        float bia = 0.f;
        if (r >= 0) {
            float ab = 0.f;
            for (int m = 0; m < Hn; ++m) {
                const float wi = w_ih[r * Hn + m];
                swc[0] += wi * fc0_w[m * 3 + 0];
                swc[1] += wi * fc0_w[m * 3 + 1];
                swc[2] += wi * fc0_w[m * 3 + 2];
                ab     += wi * fc0_b[m];
            }
            swc[0] *= s; swc[1] *= s; swc[2] *= s;
            bia = s * (ab + b_ih[r] + b_hh[r]);
        }
        #pragma unroll
        for (int ks = 0; ks < 2; ++ks) {
            f16x8 f;
            #pragma unroll
            for (int e = 0; e < 8; ++e) {
                const int k = ks * 32 + kg * 8 + e;
                float val = 0.f;
                if (r >= 0) {
                    if (k < 34)       val = s * w_hh[r * Hn + k];
                    else if (k < 37)  val = swc[k - 34];
                    else if (k < 40)  val = swc[k - 37];
                    else if (k == 40) val = bia;                          // bias_h
                    else if (k == 41) val = bia - (float)(_Float16)bia;   // bias_l
                }
                f[e] = (_Float16)val;
            }
            Wt[tau][ks] = f;
        }
    }

    // lane-local cells: jl = 4*tau + kg (tau=0,1 always valid; tau=2 iff 8+kg < nc)
    const bool has2 = (8 + kg < nc);
    float c0 = 0.f, c1 = 0.f, c2 = 0.f;

    // x staging: wave w stages batches 4w..4w+3 (12 lanes x 1 feature)
    const bool xact = (lane < 12);
    const int bx = 4 * wv + lane / 3;
    const int ix = lane - 3 * (lane / 3);

    // output-gather jobs: 16 rows x 9 chunks (8 x float4 + 1 x float2) = 144
    const int sb = tid / 9;
    const int mj = tid - sb * 9;
    const bool oact = (tid < 144);

    // ---- zero both A buffers; barrier; bias-1.0 slots + x(0); barrier ----
    for (int i = tid; i < 2 * GB * KP; i += 256) ((_Float16*)a_lds)[i] = (_Float16)0.f;
    block_sync_lds();

    const long long bg = (long long)blockIdx.x * GB;
    const float* xblk = x + bg * (long long)(Tn * 3);
    float* oblk = out + bg * (long long)(Tn * Hn);
    const long long TH = (long long)Tn * Hn;

    if (tid < 32) {   // constant-1.0 slots (bias path), both buffers
        a_lds[tid >> 4][tid & 15][40] = (_Float16)1.f;
        a_lds[tid >> 4][tid & 15][41] = (_Float16)1.f;
    }
    if (xact) {
        const float xr = xblk[bx * (Tn * 3) + ix];
        const _Float16 xh = (_Float16)xr;
        a_lds[0][bx][34 + ix] = xh;
        a_lds[0][bx][37 + ix] = (_Float16)(xr - (float)xh);
    }
    block_sync_lds();

    float* orow = oblk + (long long)sb * TH;   // cursor: row (sb, t-1)

    for (int t = 0; t < Tn; ++t) {
        const int cur = t & 1, nxt = cur ^ 1;

        // ---- data B-fragments first (feed MFMA; return before gather reads) ----
        f16x8 av[2];
        #pragma unroll
        for (int ks = 0; ks < 2; ++ks)
            av[ks] = *(const f16x8*)(&a_lds[cur][b][ks * 32 + kg * 8]);

        // ---- coalesced output of h(t-1): gather from a_lds[cur] (read-only) ----
        if (t && oact) {
            if (mj < 8) {
                const h16x4 hv = *(const h16x4*)(&a_lds[cur][sb][4 * mj]);
                f32x4u o;
                o[0] = (float)hv[0]; o[1] = (float)hv[1];
                o[2] = (float)hv[2]; o[3] = (float)hv[3];
                *(f32x4u*)(orow + 4 * mj) = o;
            } else {
                const h16x2 hv = *(const h16x2*)(&a_lds[cur][sb][32]);
                f32x2u o; o[0] = (float)hv[0]; o[1] = (float)hv[1];
                *(f32x2u*)(orow + 32) = o;
            }
        }
        if (t) orow += Hn;

        // prefetch next step's x
        float xr = 0.f;
        if (xact && t + 1 < Tn)
            xr = xblk[bx * (Tn * 3) + (t + 1) * 3 + ix];

        // ---- MFMA (swapped): acc[tau] regs = gates i,f,g,o of cell 4*tau+kg ----
        f32x4 acc[3];
        #pragma unroll
        for (int tau = 0; tau < 3; ++tau) {
            acc[tau] = f32x4{0.f, 0.f, 0.f, 0.f};
            #pragma unroll
            for (int ks = 0; ks < 2; ++ks)
                acc[tau] = __builtin_amdgcn_mfma_f32_16x16x32_f16(Wt[tau][ks], av[ks], acc[tau], 0, 0, 0);
        }

        // ---- lane-local nonlinearity + cell update (gate = reg index, static) ----
        {
            const float gi = frcp(1.f + fexp2(acc[0][0]));
            const float gf = frcp(1.f + fexp2(acc[0][1]));
            const float gg = fmaf(-2.f, frcp(1.f + fexp2(acc[0][2])), 1.f);
            const float go = frcp(1.f + fexp2(acc[0][3]));
            c0 = gf * c0 + gi * gg;
            const float h = go * fmaf(-2.f, frcp(1.f + fexp2(c0 * (2.f * L2E))), 1.f);
            a_lds[nxt][b][base + kg] = (_Float16)h;
        }
        {
            const float gi = frcp(1.f + fexp2(acc[1][0]));
            const float gf = frcp(1.f + fexp2(acc[1][1]));
            const float gg = fmaf(-2.f, frcp(1.f + fexp2(acc[1][2])), 1.f);
            const float go = frcp(1.f + fexp2(acc[1][3]));
            c1 = gf * c1 + gi * gg;
            const float h = go * fmaf(-2.f, frcp(1.f + fexp2(c1 * (2.f * L2E))), 1.f);
            a_lds[nxt][b][base + 4 + kg] = (_Float16)h;
        }
        if (has2) {
            const float gi = frcp(1.f + fexp2(acc[2][0]));
            const float gf = frcp(1.f + fexp2(acc[2][1]));
            const float gg = fmaf(-2.f, frcp(1.f + fexp2(acc[2][2])), 1.f);
            const float go = frcp(1.f + fexp2(acc[2][3]));
            c2 = gf * c2 + gi * gg;
            const float h = go * fmaf(-2.f, frcp(1.f + fexp2(c2 * (2.f * L2E))), 1.f);
            a_lds[nxt][b][base + 8 + kg] = (_Float16)h;
        }

        // ---- stage x(t+1) into next A buffer ----
        if (xact) {
            const _Float16 xh = (_Float16)xr;
            a_lds[nxt][bx][34 + ix] = xh;
            a_lds[nxt][bx][37 + ix] = (_Float16)(xr - (float)xh);
        }

        block_sync_lds();   // the ONE sync/step: h(t) visible to all waves
    }

    // ---- epilogue: flush h(Tn-1) (in buffer Tn&1; prior barrier drained writes) ----
    if (oact) {
        const int fin = Tn & 1;
        if (mj < 8) {
            const h16x4 hv = *(const h16x4*)(&a_lds[fin][sb][4 * mj]);
            f32x4u o;
            o[0] = (float)hv[0]; o[1] = (float)hv[1];
            o[2] = (float)hv[2]; o[3] = (float)hv[3];
            *(f32x4u*)(orow + 4 * mj) = o;
        } else {
            const h16x2 hv = *(const h16x2*)(&a_lds[fin][sb][32]);
            f32x2u o; o[0] = (float)hv[0]; o[1] = (float)hv[1];
            *(f32x2u*)(orow + 32) = o;
        }
    }
}

} // namespace

extern "C" void kernel_launch(void* const* d_in, const int* in_sizes, int n_in,
                              void* d_out, int out_size, void* d_ws, size_t ws_size,
                              hipStream_t stream) {
    const float* x     = (const float*)d_in[0];
    const float* fc0_w = (const float*)d_in[1];
    const float* fc0_b = (const float*)d_in[2];
    const float* w_ih  = (const float*)d_in[3];
    const float* w_hh  = (const float*)d_in[4];
    const float* b_ih  = (const float*)d_in[5];
    const float* b_hh  = (const float*)d_in[6];
    float* out = (float*)d_out;

    lstm_kernel<<<Bn / GB, 256, 0, stream>>>(x, fc0_w, fc0_b, w_ih, w_hh, b_ih, b_hh, out);
}

// Round 20
// 351.913 us; speedup vs baseline: 1.0556x; 1.0556x over previous
//
#include <hip/hip_runtime.h>

namespace {

constexpr int Bn = 8192;
constexpr int Tn = 365;
constexpr int Hn = 34;
constexpr int GB = 16;      // batches per block -> grid 512, 2 blocks/CU
constexpr int KP = 72;      // a_lds row stride in halves (144 B; 2-way banks)

constexpr float L2E = 1.44269504088896340736f;

typedef __attribute__((ext_vector_type(8))) _Float16 f16x8;  // 8 fp16 = 4 VGPR
typedef __attribute__((ext_vector_type(4))) float f32x4;     // 16x16 MFMA acc

__device__ __forceinline__ float fexp2(float v) { return __builtin_amdgcn_exp2f(v); }
__device__ __forceinline__ float frcp(float v)  { return __builtin_amdgcn_rcpf(v); }

// cross-wave LDS barrier WITHOUT a vmcnt drain: LDS writes drained (lgkmcnt),
// then raw s_barrier. Global stores/loads stay in flight across steps.
__device__ __forceinline__ void block_sync_lds() {
    __builtin_amdgcn_sched_barrier(0);
    asm volatile("s_waitcnt lgkmcnt(0)" ::: "memory");
    __builtin_amdgcn_s_barrier();
    __builtin_amdgcn_sched_barrier(0);
}

// FP16 K-layout (42 used of 64; pads stay zero). fp16 (e5m10): h,x,w in [-5,5]
// mid-range; fp16 products exact in f32 MFMA accumulate. Weight rows
// PRE-SCALED by s(gate): -log2e (i,f,o) / +2*log2e (g):
//   sigmoid = rcp(1+exp2(acc)),  tanh = fma(-2, rcp(1+exp2(acc)), 1).
//   k 0-33 : h[j]   <-> fp16(s*w_hh[r][j])
//   k 34-36: x_h[i] <-> fp16(s*Wc[r][i])
//   k 37-39: x_l[i] <-> fp16(s*Wc[r][i])     (x_l = x - fp16(x))
//   k 40   : 1.0    <-> bias_h ;  k 41 : 1.0 <-> bias_l
//
// SWAPPED-OPERAND MFMA (R16): lane (kg,b) holds gates i,f,g,o of cell
// jl = 4*tau+kg, batch b -> cell update LANE-LOCAL. One s_barrier/step.
//
// R20: X LOAD PIPELINED 2 STEPS DEEP. vmcnt is a FIFO in issue order, so a
// same-step x-load consumed after the h-stores forces a drain of those
// scattered stores (~300-800 cyc store-retire) EVERY step — the R9-R18
// invariant stall. Holding x(t+1) in a register (loaded in step t-1) makes
// every vmem wait target ops >= 1 full step (~2300 cyc) old: free.

__global__ __launch_bounds__(256) void lstm_kernel(
    const float* __restrict__ x,      // [B,T,3]
    const float* __restrict__ fc0_w,  // [34,3]
    const float* __restrict__ fc0_b,  // [34]
    const float* __restrict__ w_ih,   // [136,34]
    const float* __restrict__ w_hh,   // [136,34]
    const float* __restrict__ b_ih,   // [136]
    const float* __restrict__ b_hh,   // [136]
    float* __restrict__ out)          // [B,T,34]
{
    __shared__ __align__(16) _Float16 a_lds[2][GB][KP]; // h/x operand, double-buffered

    const int tid  = threadIdx.x;
    const int lane = tid & 63;
    const int wv   = tid >> 6;      // wave id
    const int b    = lane & 15;     // batch (D col); tile-row rho when building W
    const int kg   = lane >> 4;     // k-group; D-row group

    // cell partition across waves: {9,9,8,8}
    const int nc   = (wv < 2) ? 9 : 8;
    const int base = (wv < 2) ? 9 * wv : 18 + 8 * (wv - 2);

    // ---- one-time: weight A-fragments (3 N-tiles x 2 K-chunks), prescaled fp16 ----
    f16x8 Wt[3][2];
    #pragma unroll
    for (int tau = 0; tau < 3; ++tau) {
        const int rhat = 16 * tau + b;
        const int jl = rhat >> 2, g = rhat & 3;
        const int r = (jl < nc) ? g * Hn + (base + jl) : -1;
        const float s = (g == 2) ? (2.f * L2E) : (-L2E);
        float swc[3] = {0.f, 0.f, 0.f};
        float bia = 0.f;
        if (r >= 0) {
            float ab = 0.f;
            for (int m = 0; m < Hn; ++m) {
                const float wi = w_ih[r * Hn + m];
                swc[0] += wi * fc0_w[m * 3 + 0];
                swc[1] += wi * fc0_w[m * 3 + 1];
                swc[2] += wi * fc0_w[m * 3 + 2];
                ab     += wi * fc0_b[m];
            }
            swc[0] *= s; swc[1] *= s; swc[2] *= s;
            bia = s * (ab + b_ih[r] + b_hh[r]);
        }
        #pragma unroll
        for (int ks = 0; ks < 2; ++ks) {
            f16x8 f;
            #pragma unroll
            for (int e = 0; e < 8; ++e) {
                const int k = ks * 32 + kg * 8 + e;
                float val = 0.f;
                if (r >= 0) {
                    if (k < 34)       val = s * w_hh[r * Hn + k];
                    else if (k < 37)  val = swc[k - 34];
                    else if (k < 40)  val = swc[k - 37];
                    else if (k == 40) val = bia;                          // bias_h
                    else if (k == 41) val = bia - (float)(_Float16)bia;   // bias_l
                }
                f[e] = (_Float16)val;
            }
            Wt[tau][ks] = f;
        }
    }

    // lane-local cells: jl = 4*tau + kg (tau=0,1 always valid; tau=2 iff 8+kg < nc)
    const bool has2 = (8 + kg < nc);
    float c0 = 0.f, c1 = 0.f, c2 = 0.f;
    float h0 = 0.f, h1 = 0.f, h2 = 0.f;

    // x staging: wave w stages batches 4w..4w+3 (12 lanes x 1 feature)
    const bool xact = (lane < 12);
    const int bx = 4 * wv + lane / 3;
    const int ix = lane - 3 * (lane / 3);

    // ---- zero both A buffers; barrier; bias-1.0 slots + x(0); barrier ----
    for (int i = tid; i < 2 * GB * KP; i += 256) ((_Float16*)a_lds)[i] = (_Float16)0.f;
    block_sync_lds();

    const long long bg = (long long)blockIdx.x * GB;
    const float* xblk = x + bg * (long long)(Tn * 3);
    float* oblk = out + bg * (long long)(Tn * Hn);
    const long long TH = (long long)Tn * Hn;

    if (tid < 32) {   // constant-1.0 slots (bias path), both buffers
        a_lds[tid >> 4][tid & 15][40] = (_Float16)1.f;
        a_lds[tid >> 4][tid & 15][41] = (_Float16)1.f;
    }
    if (xact) {
        const float xr = xblk[bx * (Tn * 3) + ix];
        const _Float16 xh = (_Float16)xr;
        a_lds[0][bx][34 + ix] = xh;
        a_lds[0][bx][37 + ix] = (_Float16)(xr - (float)xh);
    }
    block_sync_lds();

    // prime the x pipeline: xr_hold = x(1)  (staged at top of step 0 into buf 1)
    float xr_hold = 0.f;
    if (xact && 1 < Tn)
        xr_hold = xblk[bx * (Tn * 3) + 3 + ix];

    // pointer-hoisted output cursor (stores h(t-1) at top of step t)
    float* pr = oblk + (long long)b * TH + base;

    for (int t = 0; t < Tn; ++t) {
        const int cur = t & 1, nxt = cur ^ 1;

        // ---- (1) data B-fragments first (LDS in-order: reads ready earliest) ----
        f16x8 av[2];
        #pragma unroll
        for (int ks = 0; ks < 2; ++ks)
            av[ks] = *(const f16x8*)(&a_lds[cur][b][ks * 32 + kg * 8]);

        // ---- (2) stage x(t+1) from xr_hold (load is >= 1 step old: free wait) ----
        if (xact) {
            const _Float16 xh = (_Float16)xr_hold;
            a_lds[nxt][bx][34 + ix] = xh;
            a_lds[nxt][bx][37 + ix] = (_Float16)(xr_hold - (float)xh);
        }

        // ---- (3) h(t-1) stores (fire-and-forget; nothing waits on them) ----
        if (t) {
            pr[kg]     = h0;
            pr[4 + kg] = h1;
            if (has2) pr[8 + kg] = h2;
            pr += Hn;
        }

        // ---- (4) issue x(t+2) load (consumed at top of step t+1) ----
        float xr_next = 0.f;
        if (xact && t + 2 < Tn)
            xr_next = xblk[bx * (Tn * 3) + (t + 2) * 3 + ix];

        // ---- MFMA (swapped): acc[tau] regs = gates i,f,g,o of cell 4*tau+kg ----
        f32x4 acc[3];
        #pragma unroll
        for (int tau = 0; tau < 3; ++tau) {
            acc[tau] = f32x4{0.f, 0.f, 0.f, 0.f};
            #pragma unroll
            for (int ks = 0; ks < 2; ++ks)
                acc[tau] = __builtin_amdgcn_mfma_f32_16x16x32_f16(Wt[tau][ks], av[ks], acc[tau], 0, 0, 0);
        }

        // ---- lane-local nonlinearity + cell update (gate = reg index, static) ----
        {
            const float gi = frcp(1.f + fexp2(acc[0][0]));
            const float gf = frcp(1.f + fexp2(acc[0][1]));
            const float gg = fmaf(-2.f, frcp(1.f + fexp2(acc[0][2])), 1.f);
            const float go = frcp(1.f + fexp2(acc[0][3]));
            c0 = gf * c0 + gi * gg;
            h0 = go * fmaf(-2.f, frcp(1.f + fexp2(c0 * (2.f * L2E))), 1.f);
            a_lds[nxt][b][base + kg] = (_Float16)h0;
        }
        {
            const float gi = frcp(1.f + fexp2(acc[1][0]));
            const float gf = frcp(1.f + fexp2(acc[1][1]));
            const float gg = fmaf(-2.f, frcp(1.f + fexp2(acc[1][2])), 1.f);
            const float go = frcp(1.f + fexp2(acc[1][3]));
            c1 = gf * c1 + gi * gg;
            h1 = go * fmaf(-2.f, frcp(1.f + fexp2(c1 * (2.f * L2E))), 1.f);
            a_lds[nxt][b][base + 4 + kg] = (_Float16)h1;
        }
        if (has2) {
            const float gi = frcp(1.f + fexp2(acc[2][0]));
            const float gf = frcp(1.f + fexp2(acc[2][1]));
            const float gg = fmaf(-2.f, frcp(1.f + fexp2(acc[2][2])), 1.f);
            const float go = frcp(1.f + fexp2(acc[2][3]));
            c2 = gf * c2 + gi * gg;
            h2 = go * fmaf(-2.f, frcp(1.f + fexp2(c2 * (2.f * L2E))), 1.f);
            a_lds[nxt][b][base + 8 + kg] = (_Float16)h2;
        }

        xr_hold = xr_next;   // advance the x pipeline

        block_sync_lds();    // the ONE sync/step: h(t) visible to all waves
    }

    // final store: h(Tn-1)
    {
        pr[kg]     = h0;
        pr[4 + kg] = h1;
        if (has2) pr[8 + kg] = h2;
    }
}

} // namespace

extern "C" void kernel_launch(void* const* d_in, const int* in_sizes, int n_in,
                              void* d_out, int out_size, void* d_ws, size_t ws_size,
                              hipStream_t stream) {
    const float* x     = (const float*)d_in[0];
    const float* fc0_w = (const float*)d_in[1];
    const float* fc0_b = (const float*)d_in[2];
    const float* w_ih  = (const float*)d_in[3];
    const float* w_hh  = (const float*)d_in[4];
    const float* b_ih  = (const float*)d_in[5];
    const float* b_hh  = (const float*)d_in[6];
    float* out = (float*)d_out;

    lstm_kernel<<<Bn / GB, 256, 0, stream>>>(x, fc0_w, fc0_b, w_ih, w_hh, b_ih, b_hh, out);
}